// Round 9
// baseline (533.200 us; speedup 1.0000x reference)
//
#include <hip/hip_runtime.h>

typedef unsigned int uint;
typedef unsigned short ushort;
typedef _Float16 f16_t;
typedef f16_t f16x8 __attribute__((ext_vector_type(8)));
typedef ushort ushort8 __attribute__((ext_vector_type(8)));
typedef float f32x4 __attribute__((ext_vector_type(4)));

#define NN 200000
#define EE 600000
#define LL 5
#define GG 2000
#define SCAN_NB 782  // ceil(NN/256); also 200192/256 for the bin-major hist scan

__device__ __forceinline__ ushort f2h(float f) {
  f16_t h = (f16_t)f;
  return __builtin_bit_cast(ushort, h);
}
__device__ __forceinline__ float h2f(ushort u) {
  return (float)__builtin_bit_cast(f16_t, u);
}
__device__ __forceinline__ float hlo(uint u) { return h2f((ushort)(u & 0xFFFFu)); }
__device__ __forceinline__ float hhi(uint u) { return h2f((ushort)(u >> 16)); }
__device__ __forceinline__ f16x8 ld8h(const uint4* p, int idx) {
  uint4 u = p[idx];
  return __builtin_bit_cast(f16x8, u);
}
// h = relu(z*sc+sh) in packed fp16 (v_pk_fma_f16 + v_pk_max_f16)
__device__ __forceinline__ f16x8 bnrelu8(f16x8 u, f16x8 sc, f16x8 sh) {
  f16x8 r = u * sc + sh;
#pragma unroll
  for (int j = 0; j < 8; ++j) r[j] = r[j] > (f16_t)0.f ? r[j] : (f16_t)0.f;
  return r;
}

// ---------------- merged setup: weight swizzle + fp16 tables + xcode + outinit ------
__global__ void k_setup(const float* __restrict__ W1, const float* __restrict__ W2,
                        ushort* __restrict__ w1s, ushort* __restrict__ w2s,
                        const float* __restrict__ ee1, const float* __restrict__ ee2,
                        const float* __restrict__ at1, const float* __restrict__ at2,
                        ushort* __restrict__ tabh, const int* __restrict__ xidx,
                        int* __restrict__ xcode, float* __restrict__ out,
                        const float* __restrict__ bp) {
  int i = blockIdx.x * 256 + threadIdx.x;
  if (i < 40960) {  // weight swizzle, B-frag 16x16x32 order
    int lane = i & 63;
    int f = i >> 6;
    bool isW2 = false;
    if (f >= 320) { f -= 320; isW2 = true; }
    int l = f >> 6, rem = f & 63;
    ushort8 o;
    if (!isW2) {
      int kt = rem >> 4, nt = rem & 15;
      int n = nt * 16 + (lane & 15);
      int kbase = kt * 32 + (lane >> 4) * 8;
#pragma unroll
      for (int j = 0; j < 8; ++j) o[j] = f2h(W1[l * 32768 + (kbase + j) * 256 + n]);
      *(ushort8*)(w1s + f * 512 + lane * 8) = o;
    } else {
      int kt = rem >> 3, nt = rem & 7;
      int n = nt * 16 + (lane & 15);
      int kbase = kt * 32 + (lane >> 4) * 8;
#pragma unroll
      for (int j = 0; j < 8; ++j) o[j] = f2h(W2[l * 32768 + (kbase + j) * 128 + n]);
      *(ushort8*)(w2s + f * 512 + lane * 8) = o;
    }
  }
  if (i < 5760) {  // comb (packed fp16)
    int l = i / 1152, rem = i % 1152;
    int ab = rem >> 7, c = rem & 127;
    int a = ab / 3, b = ab - a * 3;
    tabh[i] = f2h(ee1[(l * 6 + a) * 128 + c] + ee2[(l * 3 + b) * 128 + c]);
  } else if (i < 6400) {  // selfv
    int j = i - 5760;
    int l = j >> 7, c = j & 127;
    tabh[i] = f2h(ee1[(l * 6 + 4) * 128 + c] + ee2[(l * 3 + 0) * 128 + c]);
  } else if (i < 7552) {  // atomc
    int j = i - 6400;
    int ab = j >> 7, c = j & 127;
    int a = ab / 3, b = ab - a * 3;
    tabh[i] = f2h(at1[a * 128 + c] + at2[b * 128 + c]);
  }
  if (i < NN) xcode[i] = xidx[2 * i] * 3 + xidx[2 * i + 1];
  if (i < GG) out[i] = bp[0];
}

// ---------------- CSR build (dst is fixed across layers) ----------------
__global__ void k_count(const int* __restrict__ ei, int* __restrict__ counts) {
  int e = blockIdx.x * 256 + threadIdx.x;
  if (e < EE) atomicAdd(&counts[ei[EE + e]], 1);
}

__global__ void k_scanA(const int* __restrict__ counts, int* __restrict__ rowptr,
                        int* __restrict__ bsums) {
  __shared__ int sd[256];
  int tid = threadIdx.x;
  int g = blockIdx.x * 256 + tid;
  int v = (g < NN) ? counts[g] : 0;
  sd[tid] = v;
  __syncthreads();
  for (int o = 1; o < 256; o <<= 1) {
    int t = (tid >= o) ? sd[tid - o] : 0;
    __syncthreads();
    sd[tid] += t;
    __syncthreads();
  }
  if (g < NN) rowptr[g] = sd[tid] - v;
  if (tid == 255) bsums[blockIdx.x] = sd[tid];
}

__global__ void k_scanB(int* __restrict__ bsums) {
  __shared__ int sd[1024];
  int tid = threadIdx.x;
  int v = (tid < SCAN_NB) ? bsums[tid] : 0;
  sd[tid] = v;
  __syncthreads();
  for (int o = 1; o < 1024; o <<= 1) {
    int t = (tid >= o) ? sd[tid - o] : 0;
    __syncthreads();
    sd[tid] += t;
    __syncthreads();
  }
  if (tid < SCAN_NB) bsums[tid] = sd[tid] - v;
}

__global__ void k_scanC(int* __restrict__ rowptr, const int* __restrict__ bsums) {
  int g = blockIdx.x * 256 + threadIdx.x;
  if (g < NN) rowptr[g] += bsums[blockIdx.x];
  if (g == 0) rowptr[NN] = EE;
}

// pack src (18b) | a9 (4b) | xcode_src (4b)
__global__ void k_fill(const int* __restrict__ ei, const int* __restrict__ ea,
                       const int* __restrict__ xcode, int* __restrict__ cursor,
                       int* __restrict__ eslot) {
  int e = blockIdx.x * 256 + threadIdx.x;
  if (e < EE) {
    int dst = ei[EE + e];
    int src = ei[e];
    int a9 = ea[2 * e] * 3 + ea[2 * e + 1];
    int sc = xcode[src];
    int pos = atomicAdd(&cursor[dst], 1);
    eslot[pos] = src | (a9 << 18) | (sc << 22);
  }
}

// ---------------- degree-balanced node order (privatized counting sort) ----------
// Privatized: per-block LDS histograms -> bin-major global -> flat scan ->
// scatter with LDS-rank. No global atomics. Descending degree (LPT order).
__global__ void k_hist2(const int* __restrict__ rowptr, int* __restrict__ bhist) {
  __shared__ int h[256];
  int tid = threadIdx.x;
  h[tid] = 0;
  __syncthreads();
  int n = blockIdx.x * 256 + tid;
  if (n < NN) {
    int d = rowptr[n + 1] - rowptr[n];
    if (d > 255) d = 255;
    atomicAdd(&h[255 - d], 1);
  }
  __syncthreads();
  bhist[tid * SCAN_NB + blockIdx.x] = h[tid];  // bin-major
}

__global__ void k_hscanA(int* __restrict__ data, int* __restrict__ bsums) {
  __shared__ int sd[256];
  int tid = threadIdx.x;
  int g = blockIdx.x * 256 + tid;
  int v = data[g];
  sd[tid] = v;
  __syncthreads();
  for (int o = 1; o < 256; o <<= 1) {
    int t = (tid >= o) ? sd[tid - o] : 0;
    __syncthreads();
    sd[tid] += t;
    __syncthreads();
  }
  data[g] = sd[tid] - v;
  if (tid == 255) bsums[blockIdx.x] = sd[tid];
}

__global__ void k_hscanC(int* __restrict__ data, const int* __restrict__ bsums) {
  int g = blockIdx.x * 256 + threadIdx.x;
  data[g] += bsums[blockIdx.x];
}

// ndesc[pos] = {node, rowstart, rowend, xcode[node]} in degree-DESC order.
// R9: also emit the inverse permutation ipos[node] = pos so z can be STORED in
// perm order (sequential self-read/write) while gather indices get translated.
__global__ void k_dfill2(const int* __restrict__ rowptr, const int* __restrict__ xcode,
                         const int* __restrict__ bpos, int4* __restrict__ ndesc,
                         int* __restrict__ ipos) {
  __shared__ int h[256];
  int tid = threadIdx.x;
  h[tid] = 0;
  __syncthreads();
  int n = blockIdx.x * 256 + tid;
  if (n < NN) {
    int s = rowptr[n], e = rowptr[n + 1];
    int d = e - s;
    if (d > 255) d = 255;
    int r = atomicAdd(&h[255 - d], 1);  // LDS rank within block
    int pos = bpos[(255 - d) * SCAN_NB + blockIdx.x] + r;
    ndesc[pos] = make_int4(n, s, e, xcode[n]);
    ipos[n] = pos;
  }
}

// translate eslot's src field (orig node id) -> perm position (z storage row)
__global__ void k_etrans(int* __restrict__ eslot, const int* __restrict__ ipos) {
  int e = blockIdx.x * 256 + threadIdx.x;
  if (e < EE) {
    int v = eslot[e];
    eslot[e] = (v & 0xFFFC0000) | ipos[v & 0x3FFFF];
  }
}

// ---------------- fused layer: packed-fp16 gather (BN affine inlined), fp16 MLP ----
// R9: z stored in PERM (degree-sorted) order. R8's byte decomposition: R7's
// 77us = scattered self-read (51MB) + scattered z-write (51MB) + random gather
// (154MB) all at the ~2.1TB/s random-access ceiling. The degree sort made
// self/write scattered (R0 had them sequential). Storing z in perm order makes
// self-read and write fully sequential (layers 0-3); gather stays random (a
// permutation of uniform-random is uniform-random). Layer 4 writes in ORIGINAL
// order (scattered, as before) so k_pool remains sequential. Numerics identical
// to R7 (pure relabeling; per-node accumulation order unchanged).
__global__ __launch_bounds__(512, 6) void k_layer(
    const ushort* __restrict__ zin, ushort* __restrict__ zout,
    const int4* __restrict__ ndesc, const ushort* __restrict__ tabh,
    const float* __restrict__ stats_in, const float* __restrict__ gamma,
    const float* __restrict__ beta,
    const int* __restrict__ eslot,
    const ushort* __restrict__ w1s, const ushort* __restrict__ w2s,
    const float* __restrict__ b1, const float* __restrict__ b2,
    float* __restrict__ stats, int layer) {
  __shared__ __align__(16) ushort BUF[64 * 264];  // 33,792 B union
  __shared__ int4 ND[64];
  __shared__ float SS[256];   // per-channel sum/sumsq staging
  __shared__ float BNP[256];  // [0..127]=scale, [128..255]=shift
  ushort* AGG = BUF;   // 64 x 136 view (gather out / stage-1 in)
  ushort* T1 = BUF;    // 64 x 264 view (stage-1 out / stage-2 in)
  ushort* ldsZ = BUF;  // 64 x 136 view (stage-2 out / store staging)
  const int tid = threadIdx.x;
  const int w = tid >> 6, lane = tid & 63;
  const int ln16 = lane & 15, sub = lane >> 4;
  const int row0 = blockIdx.x * 64;

  if (tid < 64) ND[tid] = ndesc[row0 + tid];
  if (layer > 0) {
    // in-block BN param: column tid of stats slice summed over 16 partials
    if (tid < 256) {
      const float* sb = stats_in + (size_t)(layer - 1) * 16 * 256;
      float a = 0.f;
#pragma unroll
      for (int cp = 0; cp < 16; ++cp) a += sb[cp * 256 + tid];
      SS[tid] = a;
    }
    __syncthreads();
    if (tid < 128) {
      float mu = SS[tid] * (1.0f / NN);
      float var = SS[128 + tid] * (1.0f / NN) - mu * mu;
      float sc = gamma[(layer - 1) * 128 + tid] * rsqrtf(var + 1e-5f);
      BNP[tid] = sc;
      BNP[128 + tid] = beta[(layer - 1) * 128 + tid] - mu * sc;
    }
  }
  __syncthreads();

  // ---- gather phase: packed fp16, BN affine inlined ----
  const uint4* combH = (const uint4*)(tabh + (size_t)layer * 1152);
  const uint4* atomH = (const uint4*)(tabh + 6400);
  const uint4* selfH = (const uint4*)(tabh + 5760 + layer * 128);
  const uint4* h4 = (const uint4*)zin;
  f16x8 sf = ld8h(selfH, ln16);
  f16x8 scv = {}, shv = {};
  if (layer > 0) {
#pragma unroll
    for (int j = 0; j < 8; ++j) {
      scv[j] = (f16_t)BNP[ln16 * 8 + j];
      shv[j] = (f16_t)BNP[128 + ln16 * 8 + j];
    }
  }

#pragma unroll
  for (int grp = 0; grp < 2; ++grp) {
    const int prow = w * 8 + grp * 4 + sub;  // perm-order row within block
    const int4 nd = ND[prow];
    const int s = nd.y, e = nd.z;
    f16x8 acc;
    if (layer == 0) {
      acc = ld8h(atomH, nd.w * 16 + ln16) + sf;
    } else {
      // self-read: z stored in perm order -> sequential within block
      acc = bnrelu8(ld8h(h4, (size_t)(row0 + prow) * 16 + ln16), scv, shv) + sf;
    }
    for (int base = s; base < e; base += 16) {
      int m = e - base;
      if (m > 16) m = 16;
      int slot = (ln16 < m) ? eslot[base + ln16] : 0;
      int jfull = m & ~3;
      int j = 0;
      for (; j < jfull; j += 4) {
        // branchless depth-4 batch: all shfls, then all loads, then consume
        int sl0 = __shfl(slot, sub * 16 + j + 0, 64);
        int sl1 = __shfl(slot, sub * 16 + j + 1, 64);
        int sl2 = __shfl(slot, sub * 16 + j + 2, 64);
        int sl3 = __shfl(slot, sub * 16 + j + 3, 64);
        f16x8 p0, p1, p2, p3;
        if (layer == 0) {
          p0 = ld8h(atomH, ((sl0 >> 22) & 15) * 16 + ln16);
          p1 = ld8h(atomH, ((sl1 >> 22) & 15) * 16 + ln16);
          p2 = ld8h(atomH, ((sl2 >> 22) & 15) * 16 + ln16);
          p3 = ld8h(atomH, ((sl3 >> 22) & 15) * 16 + ln16);
        } else {
          p0 = ld8h(h4, (size_t)(sl0 & 0x3FFFF) * 16 + ln16);
          p1 = ld8h(h4, (size_t)(sl1 & 0x3FFFF) * 16 + ln16);
          p2 = ld8h(h4, (size_t)(sl2 & 0x3FFFF) * 16 + ln16);
          p3 = ld8h(h4, (size_t)(sl3 & 0x3FFFF) * 16 + ln16);
        }
        f16x8 c0 = ld8h(combH, ((sl0 >> 18) & 15) * 16 + ln16);
        f16x8 c1 = ld8h(combH, ((sl1 >> 18) & 15) * 16 + ln16);
        f16x8 c2 = ld8h(combH, ((sl2 >> 18) & 15) * 16 + ln16);
        f16x8 c3 = ld8h(combH, ((sl3 >> 18) & 15) * 16 + ln16);
        if (layer != 0) {
          p0 = bnrelu8(p0, scv, shv);
          p1 = bnrelu8(p1, scv, shv);
          p2 = bnrelu8(p2, scv, shv);
          p3 = bnrelu8(p3, scv, shv);
        }
        acc += p0 + c0;
        acc += p1 + c1;
        acc += p2 + c2;
        acc += p3 + c3;
      }
      for (; j < m; ++j) {
        int sl = __shfl(slot, sub * 16 + j, 64);
        f16x8 p0;
        if (layer == 0) {
          p0 = ld8h(atomH, ((sl >> 22) & 15) * 16 + ln16);
        } else {
          p0 = bnrelu8(ld8h(h4, (size_t)(sl & 0x3FFFF) * 16 + ln16), scv, shv);
        }
        f16x8 c0 = ld8h(combH, ((sl >> 18) & 15) * 16 + ln16);
        acc += p0 + c0;
      }
    }
    *(uint4*)&AGG[prow * 136 + ln16 * 8] = __builtin_bit_cast(uint4, acc);
  }
  __syncthreads();

  // ---- MLP stage 1: acc = AGG @ W1, M=64; wave w covers n in [32w, 32w+32) ----
  const int lm = ln16, q = sub;
  f32x4 acc[4][2] = {};
  const ushort* w1b = w1s + layer * 64 * 512;
#pragma unroll
  for (int kt = 0; kt < 4; ++kt) {
    f16x8 af[4];
#pragma unroll
    for (int mt = 0; mt < 4; ++mt) {
      const ushort* p = AGG + (mt * 16 + lm) * 136 + kt * 32 + q * 8;
      af[mt] = __builtin_bit_cast(f16x8, *(const ushort8*)p);
    }
    f16x8 bf[2];
#pragma unroll
    for (int ni = 0; ni < 2; ++ni) {
      const ushort* p = w1b + (kt * 16 + w * 2 + ni) * 512 + lane * 8;
      bf[ni] = __builtin_bit_cast(f16x8, *(const ushort8*)p);
    }
#pragma unroll
    for (int mt = 0; mt < 4; ++mt)
#pragma unroll
      for (int ni = 0; ni < 2; ++ni)
        acc[mt][ni] = __builtin_amdgcn_mfma_f32_16x16x32_f16(
            af[mt], bf[ni], acc[mt][ni], 0, 0, 0);
  }
  __syncthreads();  // AGG dead; T1 may now overwrite the union buffer
#pragma unroll
  for (int nt = 0; nt < 2; ++nt) {
    int n = w * 32 + nt * 16 + lm;
    float bias = b1[layer * 256 + n];
#pragma unroll
    for (int mt = 0; mt < 4; ++mt)
#pragma unroll
      for (int r = 0; r < 4; ++r) {
        float v = fmaxf(acc[mt][nt][r] + bias, 0.0f);
        T1[(mt * 16 + q * 4 + r) * 264 + n] = f2h(v);
      }
  }
  __syncthreads();

  // ---- MLP stage 2: z = T1 @ W2 + b2; wave w covers n in [16w, 16w+16) ----
  f32x4 acc2[4] = {};
  const ushort* w2b = w2s + layer * 64 * 512;
#pragma unroll
  for (int kt = 0; kt < 8; ++kt) {
    f16x8 af[4], bf;
#pragma unroll
    for (int mt = 0; mt < 4; ++mt) {
      const ushort* p = T1 + (mt * 16 + lm) * 264 + kt * 32 + q * 8;
      af[mt] = __builtin_bit_cast(f16x8, *(const ushort8*)p);
    }
    {
      const ushort* p = w2b + (kt * 8 + w) * 512 + lane * 8;
      bf = __builtin_bit_cast(f16x8, *(const ushort8*)p);
    }
#pragma unroll
    for (int mt = 0; mt < 4; ++mt)
      acc2[mt] = __builtin_amdgcn_mfma_f32_16x16x32_f16(af[mt], bf, acc2[mt], 0, 0, 0);
  }
  __syncthreads();  // T1 dead; ldsZ may now overwrite the union buffer
  float ssum = 0.f, ssq = 0.f;
  {
    int n = w * 16 + lm;
    float bias = b2[layer * 128 + n];
#pragma unroll
    for (int mt = 0; mt < 4; ++mt)
#pragma unroll
      for (int r = 0; r < 4; ++r) {
        float v = acc2[mt][r] + bias;
        ldsZ[(mt * 16 + q * 4 + r) * 136 + n] = f2h(v);
        ssum += v;
        ssq += v * v;
      }
    ssum += __shfl_xor(ssum, 16, 64);
    ssum += __shfl_xor(ssum, 32, 64);
    ssq += __shfl_xor(ssq, 16, 64);
    ssq += __shfl_xor(ssq, 32, 64);
  }
  if (lane < 16) {
    int cp = blockIdx.x & 15;
    float* sb = stats + (size_t)(layer * 16 + cp) * 256;
    int col = w * 16 + lane;
    atomicAdd(&sb[col], ssum);
    atomicAdd(&sb[128 + col], ssq);
  }
  __syncthreads();
  // z store: layers 0-3 sequential (perm order); layer 4 original order for k_pool
  uint* zo = (uint*)zout;
  for (int i = tid; i < 64 * 64; i += 512) {
    int row = i >> 6, cpx = i & 63;
    uint v = *(const uint*)&ldsZ[row * 136 + cpx * 2];
    size_t zrow = (layer == LL - 1) ? (size_t)ND[row].x : (size_t)(row0 + row);
    zo[zrow * 64 + cpx] = v;
  }
}

// ---------------- pooling with segmented running sum (batch sorted) ----------------
// BN-4 params computed in-block from stats. z (final layer) is in ORIGINAL order.
__global__ __launch_bounds__(256) void k_pool(const ushort* __restrict__ z,
                                              const float* __restrict__ stats,
                                              const float* __restrict__ gamma,
                                              const float* __restrict__ beta,
                                              const int* __restrict__ batch,
                                              const float* __restrict__ Wp,
                                              float* __restrict__ out) {
  __shared__ float SS[256];
  __shared__ float BNP[256];
  const int tid = threadIdx.x;
  const int w = tid >> 6, lane = tid & 63;
  const int nb = blockIdx.x * 64 + w * 16;
  {
    const float* sb = stats + (size_t)4 * 16 * 256;
    float a = 0.f;
#pragma unroll
    for (int cp = 0; cp < 16; ++cp) a += sb[cp * 256 + tid];
    SS[tid] = a;
    __syncthreads();
    if (tid < 128) {
      float mu = SS[tid] * (1.0f / NN);
      float var = SS[128 + tid] * (1.0f / NN) - mu * mu;
      float sc = gamma[4 * 128 + tid] * rsqrtf(var + 1e-5f);
      BNP[tid] = sc;
      BNP[128 + tid] = beta[4 * 128 + tid] - mu * sc;
    }
    __syncthreads();
  }
  float2 wp = ((const float2*)Wp)[lane];
  float2 scv = make_float2(BNP[2 * lane], BNP[2 * lane + 1]);
  float2 shv = make_float2(BNP[128 + 2 * lane], BNP[128 + 2 * lane + 1]);
  const uint* z32 = (const uint*)z;
  int bb = (lane < 16) ? batch[nb + lane] : 0;
  int curb = __shfl(bb, 0);
  float run = 0.f;
#pragma unroll
  for (int i = 0; i < 16; ++i) {
    int b = __shfl(bb, i);
    uint u = z32[(size_t)(nb + i) * 64 + lane];
    float dot = fmaf(hlo(u), scv.x, shv.x) * wp.x + fmaf(hhi(u), scv.y, shv.y) * wp.y;
#pragma unroll
    for (int off = 32; off > 0; off >>= 1) dot += __shfl_xor(dot, off, 64);
    if (b != curb) {
      if (lane == 0) atomicAdd(&out[curb], run);
      run = 0.f;
      curb = b;
    }
    run += dot;
  }
  if (lane == 0) atomicAdd(&out[curb], run);
}

extern "C" void kernel_launch(void* const* d_in, const int* in_sizes, int n_in,
                              void* d_out, int out_size, void* d_ws, size_t ws_size,
                              hipStream_t stream) {
  (void)in_sizes; (void)n_in; (void)out_size; (void)ws_size;
  const int* xidx = (const int*)d_in[0];
  const int* eidx = (const int*)d_in[1];
  const int* eattr = (const int*)d_in[2];
  const int* batch = (const int*)d_in[3];
  const float* at1 = (const float*)d_in[4];
  const float* at2 = (const float*)d_in[5];
  const float* ee1 = (const float*)d_in[6];
  const float* ee2 = (const float*)d_in[7];
  const float* W1 = (const float*)d_in[8];
  const float* b1 = (const float*)d_in[9];
  const float* W2 = (const float*)d_in[10];
  const float* b2 = (const float*)d_in[11];
  const float* gamma = (const float*)d_in[12];
  const float* beta = (const float*)d_in[13];
  const float* Wp = (const float*)d_in[14];
  const float* bp = (const float*)d_in[15];
  float* out = (float*)d_out;

  char* ws = (char*)d_ws;
  size_t off = 0;
  auto alloc = [&](size_t bytes) -> void* {
    void* p = ws + off;
    off = (off + bytes + 255) & ~(size_t)255;
    return p;
  };
  ushort* bufA = (ushort*)alloc((size_t)NN * 128 * 2);
  ushort* bufB = (ushort*)alloc((size_t)NN * 128 * 2);
  ushort* w1s = (ushort*)alloc(320 * 512 * 2);
  ushort* w2s = (ushort*)alloc(320 * 512 * 2);
  int* rowptr = (int*)alloc((NN + 1) * 4);
  int* cursor = (int*)alloc((size_t)NN * 4);
  int* eslot = (int*)alloc((size_t)EE * 4);
  int* bsums = (int*)alloc(1024 * 4);
  ushort* tabh = (ushort*)alloc(7552 * 2);
  int* xcode = (int*)alloc((size_t)NN * 4);
  float* stats = (float*)alloc((size_t)LL * 16 * 256 * 4);
  int* bhist = (int*)alloc((size_t)SCAN_NB * 256 * 4);
  int* bsums2 = (int*)alloc(1024 * 4);
  int4* ndesc = (int4*)alloc((size_t)NN * 16);
  int* ipos = (int*)alloc((size_t)NN * 4);

  hipMemsetAsync(cursor, 0, (size_t)NN * 4, stream);
  hipMemsetAsync(stats, 0, (size_t)LL * 16 * 256 * 4, stream);
  k_setup<<<SCAN_NB, 256, 0, stream>>>(W1, W2, w1s, w2s, ee1, ee2, at1, at2, tabh, xidx,
                                       xcode, out, bp);
  k_count<<<(EE + 255) / 256, 256, 0, stream>>>(eidx, cursor);
  k_scanA<<<SCAN_NB, 256, 0, stream>>>(cursor, rowptr, bsums);
  k_scanB<<<1, 1024, 0, stream>>>(bsums);
  k_scanC<<<SCAN_NB, 256, 0, stream>>>(rowptr, bsums);
  hipMemcpyAsync(cursor, rowptr, (size_t)NN * 4, hipMemcpyDeviceToDevice, stream);
  k_fill<<<(EE + 255) / 256, 256, 0, stream>>>(eidx, eattr, xcode, cursor, eslot);
  // degree-balanced node ordering (privatized counting sort, descending degree)
  k_hist2<<<SCAN_NB, 256, 0, stream>>>(rowptr, bhist);
  k_hscanA<<<SCAN_NB, 256, 0, stream>>>(bhist, bsums2);
  k_scanB<<<1, 1024, 0, stream>>>(bsums2);
  k_hscanC<<<SCAN_NB, 256, 0, stream>>>(bhist, bsums2);
  k_dfill2<<<SCAN_NB, 256, 0, stream>>>(rowptr, xcode, bhist, ndesc, ipos);
  k_etrans<<<(EE + 255) / 256, 256, 0, stream>>>(eslot, ipos);

  for (int l = 0; l < LL; ++l) {
    ushort* zo = (l & 1) ? bufB : bufA;
    const ushort* zi = (l & 1) ? bufA : bufB;  // raw z_{l-1}; unused for l==0
    k_layer<<<NN / 64, 512, 0, stream>>>((l == 0) ? bufA : zi, zo, ndesc, tabh, stats,
                                         gamma, beta, eslot, w1s, w2s, b1, b2,
                                         stats, l);
  }
  k_pool<<<NN / 64, 256, 0, stream>>>(bufA, stats, gamma, beta, batch, Wp, out);
}

// Round 10
// 516.773 us; speedup vs baseline: 1.0318x; 1.0318x over previous
//
#include <hip/hip_runtime.h>

typedef unsigned int uint;
typedef unsigned short ushort;
typedef _Float16 f16_t;
typedef f16_t f16x8 __attribute__((ext_vector_type(8)));
typedef ushort ushort8 __attribute__((ext_vector_type(8)));
typedef float f32x4 __attribute__((ext_vector_type(4)));

#define NN 200000
#define EE 600000
#define LL 5
#define GG 2000
#define SCAN_NB 782  // ceil(NN/256); also 200192/256 for the bin-major hist scan

__device__ __forceinline__ ushort f2h(float f) {
  f16_t h = (f16_t)f;
  return __builtin_bit_cast(ushort, h);
}
__device__ __forceinline__ float h2f(ushort u) {
  return (float)__builtin_bit_cast(f16_t, u);
}
__device__ __forceinline__ float hlo(uint u) { return h2f((ushort)(u & 0xFFFFu)); }
__device__ __forceinline__ float hhi(uint u) { return h2f((ushort)(u >> 16)); }
__device__ __forceinline__ f16x8 ld8h(const uint4* p, int idx) {
  uint4 u = p[idx];
  return __builtin_bit_cast(f16x8, u);
}
// h = relu(z*sc+sh) in packed fp16 (v_pk_fma_f16 + v_pk_max_f16)
__device__ __forceinline__ f16x8 bnrelu8(f16x8 u, f16x8 sc, f16x8 sh) {
  f16x8 r = u * sc + sh;
#pragma unroll
  for (int j = 0; j < 8; ++j) r[j] = r[j] > (f16_t)0.f ? r[j] : (f16_t)0.f;
  return r;
}

// ---------------- merged setup: weight swizzle + fp16 tables + xcode + outinit ------
// R10: also absorbs k_count (grid-stride edge histogram into counts).
__global__ void k_setup(const float* __restrict__ W1, const float* __restrict__ W2,
                        ushort* __restrict__ w1s, ushort* __restrict__ w2s,
                        const float* __restrict__ ee1, const float* __restrict__ ee2,
                        const float* __restrict__ at1, const float* __restrict__ at2,
                        ushort* __restrict__ tabh, const int* __restrict__ xidx,
                        int* __restrict__ xcode, float* __restrict__ out,
                        const float* __restrict__ bp, const int* __restrict__ ei,
                        int* __restrict__ counts) {
  int i = blockIdx.x * 256 + threadIdx.x;
  if (i < 40960) {  // weight swizzle, B-frag 16x16x32 order
    int lane = i & 63;
    int f = i >> 6;
    bool isW2 = false;
    if (f >= 320) { f -= 320; isW2 = true; }
    int l = f >> 6, rem = f & 63;
    ushort8 o;
    if (!isW2) {
      int kt = rem >> 4, nt = rem & 15;
      int n = nt * 16 + (lane & 15);
      int kbase = kt * 32 + (lane >> 4) * 8;
#pragma unroll
      for (int j = 0; j < 8; ++j) o[j] = f2h(W1[l * 32768 + (kbase + j) * 256 + n]);
      *(ushort8*)(w1s + f * 512 + lane * 8) = o;
    } else {
      int kt = rem >> 3, nt = rem & 7;
      int n = nt * 16 + (lane & 15);
      int kbase = kt * 32 + (lane >> 4) * 8;
#pragma unroll
      for (int j = 0; j < 8; ++j) o[j] = f2h(W2[l * 32768 + (kbase + j) * 128 + n]);
      *(ushort8*)(w2s + f * 512 + lane * 8) = o;
    }
  }
  if (i < 5760) {  // comb (packed fp16)
    int l = i / 1152, rem = i % 1152;
    int ab = rem >> 7, c = rem & 127;
    int a = ab / 3, b = ab - a * 3;
    tabh[i] = f2h(ee1[(l * 6 + a) * 128 + c] + ee2[(l * 3 + b) * 128 + c]);
  } else if (i < 6400) {  // selfv
    int j = i - 5760;
    int l = j >> 7, c = j & 127;
    tabh[i] = f2h(ee1[(l * 6 + 4) * 128 + c] + ee2[(l * 3 + 0) * 128 + c]);
  } else if (i < 7552) {  // atomc
    int j = i - 6400;
    int ab = j >> 7, c = j & 127;
    int a = ab / 3, b = ab - a * 3;
    tabh[i] = f2h(at1[a * 128 + c] + at2[b * 128 + c]);
  }
  if (i < NN) xcode[i] = xidx[2 * i] * 3 + xidx[2 * i + 1];
  if (i < GG) out[i] = bp[0];
  // degree counting (was k_count): grid-stride over edges
  for (int e = i; e < EE; e += SCAN_NB * 256) atomicAdd(&counts[ei[EE + e]], 1);
}

// ---------------- CSR build (dst is fixed across layers) ----------------
// R10: scanA also builds the per-block degree histogram (was k_hist2) —
// v IS the degree of node g, so the extra pass over counts is free here.
__global__ void k_scanA(const int* __restrict__ counts, int* __restrict__ rowptr,
                        int* __restrict__ bsums, int* __restrict__ bhist) {
  __shared__ int sd[256];
  __shared__ int h[256];
  int tid = threadIdx.x;
  int g = blockIdx.x * 256 + tid;
  int v = (g < NN) ? counts[g] : 0;
  sd[tid] = v;
  h[tid] = 0;
  __syncthreads();
  if (g < NN) {
    int d = v > 255 ? 255 : v;
    atomicAdd(&h[255 - d], 1);  // descending-degree bin (LPT order)
  }
  for (int o = 1; o < 256; o <<= 1) {
    int t = (tid >= o) ? sd[tid - o] : 0;
    __syncthreads();
    sd[tid] += t;
    __syncthreads();
  }
  if (g < NN) rowptr[g] = sd[tid] - v;
  if (tid == 255) bsums[blockIdx.x] = sd[tid];
  bhist[tid * SCAN_NB + blockIdx.x] = h[tid];  // bin-major
}

__global__ void k_scanB(int* __restrict__ bsums) {
  __shared__ int sd[1024];
  int tid = threadIdx.x;
  int v = (tid < SCAN_NB) ? bsums[tid] : 0;
  sd[tid] = v;
  __syncthreads();
  for (int o = 1; o < 1024; o <<= 1) {
    int t = (tid >= o) ? sd[tid - o] : 0;
    __syncthreads();
    sd[tid] += t;
    __syncthreads();
  }
  if (tid < SCAN_NB) bsums[tid] = sd[tid] - v;
}

__global__ void k_scanC(int* __restrict__ rowptr, const int* __restrict__ bsums) {
  int g = blockIdx.x * 256 + threadIdx.x;
  if (g < NN) rowptr[g] += bsums[blockIdx.x];
  if (g == 0) rowptr[NN] = EE;
}

// pack src (18b) | a9 (4b) | xcode_src (4b)
__global__ void k_fill(const int* __restrict__ ei, const int* __restrict__ ea,
                       const int* __restrict__ xcode, int* __restrict__ cursor,
                       int* __restrict__ eslot) {
  int e = blockIdx.x * 256 + threadIdx.x;
  if (e < EE) {
    int dst = ei[EE + e];
    int src = ei[e];
    int a9 = ea[2 * e] * 3 + ea[2 * e + 1];
    int sc = xcode[src];
    int pos = atomicAdd(&cursor[dst], 1);
    eslot[pos] = src | (a9 << 18) | (sc << 22);
  }
}

// in-place exclusive scan over 782*256 = 200192 entries (exact multiple of 256)
__global__ void k_hscanA(int* __restrict__ data, int* __restrict__ bsums) {
  __shared__ int sd[256];
  int tid = threadIdx.x;
  int g = blockIdx.x * 256 + tid;
  int v = data[g];
  sd[tid] = v;
  __syncthreads();
  for (int o = 1; o < 256; o <<= 1) {
    int t = (tid >= o) ? sd[tid - o] : 0;
    __syncthreads();
    sd[tid] += t;
    __syncthreads();
  }
  data[g] = sd[tid] - v;
  if (tid == 255) bsums[blockIdx.x] = sd[tid];
}

__global__ void k_hscanC(int* __restrict__ data, const int* __restrict__ bsums) {
  int g = blockIdx.x * 256 + threadIdx.x;
  data[g] += bsums[blockIdx.x];
}

// ndesc[pos] = {node, rowstart, rowend, xcode[node]} in degree-DESC order.
// R10: also writes cursor[n] = rowstart (replaces the rowptr->cursor memcpy).
__global__ void k_dfill2(const int* __restrict__ rowptr, const int* __restrict__ xcode,
                         const int* __restrict__ bpos, int4* __restrict__ ndesc,
                         int* __restrict__ cursor) {
  __shared__ int h[256];
  int tid = threadIdx.x;
  h[tid] = 0;
  __syncthreads();
  int n = blockIdx.x * 256 + tid;
  if (n < NN) {
    int s = rowptr[n], e = rowptr[n + 1];
    cursor[n] = s;
    int d = e - s;
    if (d > 255) d = 255;
    int r = atomicAdd(&h[255 - d], 1);  // LDS rank within block
    int pos = bpos[(255 - d) * SCAN_NB + blockIdx.x] + r;
    ndesc[pos] = make_int4(n, s, e, xcode[n]);
  }
}

// ---------------- fused layer: packed-fp16 gather (BN affine inlined), fp16 MLP ----
// R7 configuration (best measured: 519us total, k_layer 76.8us) — byte-wall
// analysis (R0-R9): k_layer dur == (FETCH+WRITE)/~2.1TB/s across 9 structural
// variants (occupancy, ILP, balance, tile size, layout all no-ops on bytes/s).
// fp8 (R8) failed precision; perm-store (R9) identical bytes, no gain. k_layer
// is ~5% above the empirical random-access ceiling -> frozen this round.
// M=64 per block (512 threads, 8 waves); weight traffic 400MB/layer (halved vs
// M=32); launch_bounds (512,6): VGPR 40, LDS 36.9KB, 3 blocks/CU.
__global__ __launch_bounds__(512, 6) void k_layer(
    const ushort* __restrict__ zin, ushort* __restrict__ zout,
    const int4* __restrict__ ndesc, const ushort* __restrict__ tabh,
    const float* __restrict__ stats_in, const float* __restrict__ gamma,
    const float* __restrict__ beta,
    const int* __restrict__ eslot,
    const ushort* __restrict__ w1s, const ushort* __restrict__ w2s,
    const float* __restrict__ b1, const float* __restrict__ b2,
    float* __restrict__ stats, int layer) {
  __shared__ __align__(16) ushort BUF[64 * 264];  // 33,792 B union
  __shared__ int4 ND[64];
  __shared__ float SS[256];   // per-channel sum/sumsq staging
  __shared__ float BNP[256];  // [0..127]=scale, [128..255]=shift
  ushort* AGG = BUF;   // 64 x 136 view (gather out / stage-1 in)
  ushort* T1 = BUF;    // 64 x 264 view (stage-1 out / stage-2 in)
  ushort* ldsZ = BUF;  // 64 x 136 view (stage-2 out / store staging)
  const int tid = threadIdx.x;
  const int w = tid >> 6, lane = tid & 63;
  const int ln16 = lane & 15, sub = lane >> 4;
  const int row0 = blockIdx.x * 64;

  if (tid < 64) ND[tid] = ndesc[row0 + tid];
  if (layer > 0) {
    // in-block BN param: column tid of stats slice summed over 16 partials
    if (tid < 256) {
      const float* sb = stats_in + (size_t)(layer - 1) * 16 * 256;
      float a = 0.f;
#pragma unroll
      for (int cp = 0; cp < 16; ++cp) a += sb[cp * 256 + tid];
      SS[tid] = a;
    }
    __syncthreads();
    if (tid < 128) {
      float mu = SS[tid] * (1.0f / NN);
      float var = SS[128 + tid] * (1.0f / NN) - mu * mu;
      float sc = gamma[(layer - 1) * 128 + tid] * rsqrtf(var + 1e-5f);
      BNP[tid] = sc;
      BNP[128 + tid] = beta[(layer - 1) * 128 + tid] - mu * sc;
    }
  }
  __syncthreads();

  // ---- gather phase: packed fp16, BN affine inlined ----
  const uint4* combH = (const uint4*)(tabh + (size_t)layer * 1152);
  const uint4* atomH = (const uint4*)(tabh + 6400);
  const uint4* selfH = (const uint4*)(tabh + 5760 + layer * 128);
  const uint4* h4 = (const uint4*)zin;
  f16x8 sf = ld8h(selfH, ln16);
  f16x8 scv = {}, shv = {};
  if (layer > 0) {
#pragma unroll
    for (int j = 0; j < 8; ++j) {
      scv[j] = (f16_t)BNP[ln16 * 8 + j];
      shv[j] = (f16_t)BNP[128 + ln16 * 8 + j];
    }
  }

#pragma unroll
  for (int grp = 0; grp < 2; ++grp) {
    const int4 nd = ND[w * 8 + grp * 4 + sub];
    const int n = nd.x;
    const int s = nd.y, e = nd.z;
    f16x8 acc;
    if (layer == 0) {
      acc = ld8h(atomH, nd.w * 16 + ln16) + sf;
    } else {
      acc = bnrelu8(ld8h(h4, (size_t)n * 16 + ln16), scv, shv) + sf;
    }
    for (int base = s; base < e; base += 16) {
      int m = e - base;
      if (m > 16) m = 16;
      int slot = (ln16 < m) ? eslot[base + ln16] : 0;
      int jfull = m & ~3;
      int j = 0;
      for (; j < jfull; j += 4) {
        // branchless depth-4 batch: all shfls, then all loads, then consume
        int sl0 = __shfl(slot, sub * 16 + j + 0, 64);
        int sl1 = __shfl(slot, sub * 16 + j + 1, 64);
        int sl2 = __shfl(slot, sub * 16 + j + 2, 64);
        int sl3 = __shfl(slot, sub * 16 + j + 3, 64);
        f16x8 p0, p1, p2, p3;
        if (layer == 0) {
          p0 = ld8h(atomH, ((sl0 >> 22) & 15) * 16 + ln16);
          p1 = ld8h(atomH, ((sl1 >> 22) & 15) * 16 + ln16);
          p2 = ld8h(atomH, ((sl2 >> 22) & 15) * 16 + ln16);
          p3 = ld8h(atomH, ((sl3 >> 22) & 15) * 16 + ln16);
        } else {
          p0 = ld8h(h4, (size_t)(sl0 & 0x3FFFF) * 16 + ln16);
          p1 = ld8h(h4, (size_t)(sl1 & 0x3FFFF) * 16 + ln16);
          p2 = ld8h(h4, (size_t)(sl2 & 0x3FFFF) * 16 + ln16);
          p3 = ld8h(h4, (size_t)(sl3 & 0x3FFFF) * 16 + ln16);
        }
        f16x8 c0 = ld8h(combH, ((sl0 >> 18) & 15) * 16 + ln16);
        f16x8 c1 = ld8h(combH, ((sl1 >> 18) & 15) * 16 + ln16);
        f16x8 c2 = ld8h(combH, ((sl2 >> 18) & 15) * 16 + ln16);
        f16x8 c3 = ld8h(combH, ((sl3 >> 18) & 15) * 16 + ln16);
        if (layer != 0) {
          p0 = bnrelu8(p0, scv, shv);
          p1 = bnrelu8(p1, scv, shv);
          p2 = bnrelu8(p2, scv, shv);
          p3 = bnrelu8(p3, scv, shv);
        }
        acc += p0 + c0;
        acc += p1 + c1;
        acc += p2 + c2;
        acc += p3 + c3;
      }
      for (; j < m; ++j) {
        int sl = __shfl(slot, sub * 16 + j, 64);
        f16x8 p0;
        if (layer == 0) {
          p0 = ld8h(atomH, ((sl >> 22) & 15) * 16 + ln16);
        } else {
          p0 = bnrelu8(ld8h(h4, (size_t)(sl & 0x3FFFF) * 16 + ln16), scv, shv);
        }
        f16x8 c0 = ld8h(combH, ((sl >> 18) & 15) * 16 + ln16);
        acc += p0 + c0;
      }
    }
    *(uint4*)&AGG[(w * 8 + grp * 4 + sub) * 136 + ln16 * 8] =
        __builtin_bit_cast(uint4, acc);
  }
  __syncthreads();

  // ---- MLP stage 1: acc = AGG @ W1, M=64; wave w covers n in [32w, 32w+32) ----
  const int lm = ln16, q = sub;
  f32x4 acc[4][2] = {};
  const ushort* w1b = w1s + layer * 64 * 512;
#pragma unroll
  for (int kt = 0; kt < 4; ++kt) {
    f16x8 af[4];
#pragma unroll
    for (int mt = 0; mt < 4; ++mt) {
      const ushort* p = AGG + (mt * 16 + lm) * 136 + kt * 32 + q * 8;
      af[mt] = __builtin_bit_cast(f16x8, *(const ushort8*)p);
    }
    f16x8 bf[2];
#pragma unroll
    for (int ni = 0; ni < 2; ++ni) {
      const ushort* p = w1b + (kt * 16 + w * 2 + ni) * 512 + lane * 8;
      bf[ni] = __builtin_bit_cast(f16x8, *(const ushort8*)p);
    }
#pragma unroll
    for (int mt = 0; mt < 4; ++mt)
#pragma unroll
      for (int ni = 0; ni < 2; ++ni)
        acc[mt][ni] = __builtin_amdgcn_mfma_f32_16x16x32_f16(
            af[mt], bf[ni], acc[mt][ni], 0, 0, 0);
  }
  __syncthreads();  // AGG dead; T1 may now overwrite the union buffer
#pragma unroll
  for (int nt = 0; nt < 2; ++nt) {
    int n = w * 32 + nt * 16 + lm;
    float bias = b1[layer * 256 + n];
#pragma unroll
    for (int mt = 0; mt < 4; ++mt)
#pragma unroll
      for (int r = 0; r < 4; ++r) {
        float v = fmaxf(acc[mt][nt][r] + bias, 0.0f);
        T1[(mt * 16 + q * 4 + r) * 264 + n] = f2h(v);
      }
  }
  __syncthreads();

  // ---- MLP stage 2: z = T1 @ W2 + b2; wave w covers n in [16w, 16w+16) ----
  f32x4 acc2[4] = {};
  const ushort* w2b = w2s + layer * 64 * 512;
#pragma unroll
  for (int kt = 0; kt < 8; ++kt) {
    f16x8 af[4], bf;
#pragma unroll
    for (int mt = 0; mt < 4; ++mt) {
      const ushort* p = T1 + (mt * 16 + lm) * 264 + kt * 32 + q * 8;
      af[mt] = __builtin_bit_cast(f16x8, *(const ushort8*)p);
    }
    {
      const ushort* p = w2b + (kt * 8 + w) * 512 + lane * 8;
      bf = __builtin_bit_cast(f16x8, *(const ushort8*)p);
    }
#pragma unroll
    for (int mt = 0; mt < 4; ++mt)
      acc2[mt] = __builtin_amdgcn_mfma_f32_16x16x32_f16(af[mt], bf, acc2[mt], 0, 0, 0);
  }
  __syncthreads();  // T1 dead; ldsZ may now overwrite the union buffer
  float ssum = 0.f, ssq = 0.f;
  {
    int n = w * 16 + lm;
    float bias = b2[layer * 128 + n];
#pragma unroll
    for (int mt = 0; mt < 4; ++mt)
#pragma unroll
      for (int r = 0; r < 4; ++r) {
        float v = acc2[mt][r] + bias;
        ldsZ[(mt * 16 + q * 4 + r) * 136 + n] = f2h(v);
        ssum += v;
        ssq += v * v;
      }
    ssum += __shfl_xor(ssum, 16, 64);
    ssum += __shfl_xor(ssum, 32, 64);
    ssq += __shfl_xor(ssq, 16, 64);
    ssq += __shfl_xor(ssq, 32, 64);
  }
  if (lane < 16) {
    int cp = blockIdx.x & 15;
    float* sb = stats + (size_t)(layer * 16 + cp) * 256;
    int col = w * 16 + lane;
    atomicAdd(&sb[col], ssum);
    atomicAdd(&sb[128 + col], ssq);
  }
  __syncthreads();
  uint* zo = (uint*)zout;
  for (int i = tid; i < 64 * 64; i += 512) {
    int row = i >> 6, cpx = i & 63;
    uint v = *(const uint*)&ldsZ[row * 136 + cpx * 2];
    zo[(size_t)ND[row].x * 64 + cpx] = v;
  }
}

// ---------------- pooling with segmented running sum (batch sorted) ----------------
// BN-4 params computed in-block from stats (replaces last k_bnparam launch).
__global__ __launch_bounds__(256) void k_pool(const ushort* __restrict__ z,
                                              const float* __restrict__ stats,
                                              const float* __restrict__ gamma,
                                              const float* __restrict__ beta,
                                              const int* __restrict__ batch,
                                              const float* __restrict__ Wp,
                                              float* __restrict__ out) {
  __shared__ float SS[256];
  __shared__ float BNP[256];
  const int tid = threadIdx.x;
  const int w = tid >> 6, lane = tid & 63;
  const int nb = blockIdx.x * 64 + w * 16;
  {
    const float* sb = stats + (size_t)4 * 16 * 256;
    float a = 0.f;
#pragma unroll
    for (int cp = 0; cp < 16; ++cp) a += sb[cp * 256 + tid];
    SS[tid] = a;
    __syncthreads();
    if (tid < 128) {
      float mu = SS[tid] * (1.0f / NN);
      float var = SS[128 + tid] * (1.0f / NN) - mu * mu;
      float sc = gamma[4 * 128 + tid] * rsqrtf(var + 1e-5f);
      BNP[tid] = sc;
      BNP[128 + tid] = beta[4 * 128 + tid] - mu * sc;
    }
    __syncthreads();
  }
  float2 wp = ((const float2*)Wp)[lane];
  float2 scv = make_float2(BNP[2 * lane], BNP[2 * lane + 1]);
  float2 shv = make_float2(BNP[128 + 2 * lane], BNP[128 + 2 * lane + 1]);
  const uint* z32 = (const uint*)z;
  int bb = (lane < 16) ? batch[nb + lane] : 0;
  int curb = __shfl(bb, 0);
  float run = 0.f;
#pragma unroll
  for (int i = 0; i < 16; ++i) {
    int b = __shfl(bb, i);
    uint u = z32[(size_t)(nb + i) * 64 + lane];
    float dot = fmaf(hlo(u), scv.x, shv.x) * wp.x + fmaf(hhi(u), scv.y, shv.y) * wp.y;
#pragma unroll
    for (int off = 32; off > 0; off >>= 1) dot += __shfl_xor(dot, off, 64);
    if (b != curb) {
      if (lane == 0) atomicAdd(&out[curb], run);
      run = 0.f;
      curb = b;
    }
    run += dot;
  }
  if (lane == 0) atomicAdd(&out[curb], run);
}

extern "C" void kernel_launch(void* const* d_in, const int* in_sizes, int n_in,
                              void* d_out, int out_size, void* d_ws, size_t ws_size,
                              hipStream_t stream) {
  (void)in_sizes; (void)n_in; (void)out_size; (void)ws_size;
  const int* xidx = (const int*)d_in[0];
  const int* eidx = (const int*)d_in[1];
  const int* eattr = (const int*)d_in[2];
  const int* batch = (const int*)d_in[3];
  const float* at1 = (const float*)d_in[4];
  const float* at2 = (const float*)d_in[5];
  const float* ee1 = (const float*)d_in[6];
  const float* ee2 = (const float*)d_in[7];
  const float* W1 = (const float*)d_in[8];
  const float* b1 = (const float*)d_in[9];
  const float* W2 = (const float*)d_in[10];
  const float* b2 = (const float*)d_in[11];
  const float* gamma = (const float*)d_in[12];
  const float* beta = (const float*)d_in[13];
  const float* Wp = (const float*)d_in[14];
  const float* bp = (const float*)d_in[15];
  float* out = (float*)d_out;

  char* ws = (char*)d_ws;
  size_t off = 0;
  auto alloc = [&](size_t bytes) -> void* {
    void* p = ws + off;
    off = (off + bytes + 255) & ~(size_t)255;
    return p;
  };
  ushort* bufA = (ushort*)alloc((size_t)NN * 128 * 2);
  ushort* bufB = (ushort*)alloc((size_t)NN * 128 * 2);
  ushort* w1s = (ushort*)alloc(320 * 512 * 2);
  ushort* w2s = (ushort*)alloc(320 * 512 * 2);
  int* rowptr = (int*)alloc((NN + 1) * 4);
  int* cursor = (int*)alloc((size_t)NN * 4);
  int* eslot = (int*)alloc((size_t)EE * 4);
  int* bsums = (int*)alloc(1024 * 4);
  ushort* tabh = (ushort*)alloc(7552 * 2);
  int* xcode = (int*)alloc((size_t)NN * 4);
  float* stats = (float*)alloc((size_t)LL * 16 * 256 * 4);
  int* bhist = (int*)alloc((size_t)SCAN_NB * 256 * 4);
  int* bsums2 = (int*)alloc(1024 * 4);
  int4* ndesc = (int4*)alloc((size_t)NN * 16);

  hipMemsetAsync(cursor, 0, (size_t)NN * 4, stream);
  hipMemsetAsync(stats, 0, (size_t)LL * 16 * 256 * 4, stream);
  // setup also counts degrees (into cursor)
  k_setup<<<SCAN_NB, 256, 0, stream>>>(W1, W2, w1s, w2s, ee1, ee2, at1, at2, tabh, xidx,
                                       xcode, out, bp, eidx, cursor);
  // rowptr scan (scanA also emits the degree histogram)
  k_scanA<<<SCAN_NB, 256, 0, stream>>>(cursor, rowptr, bsums, bhist);
  k_scanB<<<1, 1024, 0, stream>>>(bsums);
  k_scanC<<<SCAN_NB, 256, 0, stream>>>(rowptr, bsums);
  // degree-order scan chain + ndesc (dfill2 also refills cursor = rowstart)
  k_hscanA<<<SCAN_NB, 256, 0, stream>>>(bhist, bsums2);
  k_scanB<<<1, 1024, 0, stream>>>(bsums2);
  k_hscanC<<<SCAN_NB, 256, 0, stream>>>(bhist, bsums2);
  k_dfill2<<<SCAN_NB, 256, 0, stream>>>(rowptr, xcode, bhist, ndesc, cursor);
  k_fill<<<(EE + 255) / 256, 256, 0, stream>>>(eidx, eattr, xcode, cursor, eslot);

  for (int l = 0; l < LL; ++l) {
    ushort* zo = (l & 1) ? bufB : bufA;
    const ushort* zi = (l & 1) ? bufA : bufB;  // raw z_{l-1}; unused for l==0
    k_layer<<<NN / 64, 512, 0, stream>>>((l == 0) ? bufA : zi, zo, ndesc, tabh, stats,
                                         gamma, beta, eslot, w1s, w2s, b1, b2,
                                         stats, l);
  }
  k_pool<<<NN / 64, 256, 0, stream>>>(bufA, stats, gamma, beta, batch, Wp, out);
}